// Round 2
// baseline (146.748 us; speedup 1.0000x reference)
//
#include <hip/hip_runtime.h>
#include <hip/hip_bf16.h>

#define NROWS 8192
#define DIM   128
#define NPAIR (NROWS / 2)
#define CSPLIT 64
#define COLS_PER_CS (NROWS / CSPLIT)    // 128
#define NTILES (COLS_PER_CS / 16)       // 8
#define MREP   4                        // 16-row blocks per wave -> 64 rows/wave
#define ROWS_PER_BLOCK 256              // 4 waves * 64 rows

typedef __attribute__((ext_vector_type(8))) short bf16x8;
typedef __attribute__((ext_vector_type(4))) float f32x4;

__device__ inline float exp2_fast(float x) {
#if __has_builtin(__builtin_amdgcn_exp2f)
    return __builtin_amdgcn_exp2f(x);
#else
    return exp2f(x);
#endif
}

__device__ inline unsigned short f2bf(float f) {
    unsigned int u = __float_as_uint(f);
    unsigned int r = (u + 0x7fffu + ((u >> 16) & 1u)) >> 16;
    return (unsigned short)r;
}

// exp(dot/128 + 1) = e * exp2(dot * SCL), SCL = log2(e)/128.
// We bake SCL into the A operand (Xa) so the inner loop is exp2 + add only.
#define SCL_F 0.0112710550069450f      // 1.4426950408889634 / 128
#define E1_F  2.7182818284590452f

// Kernel 1: X (f32) -> Xa (bf16, scaled by SCL) and Xb (bf16, unscaled).
__global__ __launch_bounds__(256) void k_convert(const float* __restrict__ X,
                                                 unsigned short* __restrict__ Xa,
                                                 unsigned short* __restrict__ Xb) {
    int id = blockIdx.x * 256 + threadIdx.x;       // 0 .. 262143
    float4 v = reinterpret_cast<const float4*>(X)[id];
    ushort4 oa, ob;
    oa.x = f2bf(v.x * SCL_F); oa.y = f2bf(v.y * SCL_F);
    oa.z = f2bf(v.z * SCL_F); oa.w = f2bf(v.w * SCL_F);
    ob.x = f2bf(v.x); ob.y = f2bf(v.y); ob.z = f2bf(v.z); ob.w = f2bf(v.w);
    reinterpret_cast<ushort4*>(Xa)[id] = oa;
    reinterpret_cast<ushort4*>(Xb)[id] = ob;
}

// Kernel 2: partial[cs][r] = e * sum over 128-col chunk cs of exp2(SCL*dot).
__global__ __launch_bounds__(256, 4) void k_rowsum(const unsigned short* __restrict__ Xa,
                                                   const unsigned short* __restrict__ Xb,
                                                   float* __restrict__ partial) {
    const int wave = threadIdx.x >> 6;
    const int lane = threadIdx.x & 63;
    const int l15  = lane & 15;
    const int lhi  = lane >> 4;   // 0..3
    const int rowbase = blockIdx.x * ROWS_PER_BLOCK + wave * (MREP * 16);
    const int cs = blockIdx.y;
    const int colbase = cs * COLS_PER_CS;

    // A fragments (scaled copy): MREP row-blocks x 4 k-blocks, 16B each.
    bf16x8 a[MREP][4];
#pragma unroll
    for (int m = 0; m < MREP; ++m) {
        const unsigned short* arow = Xa + (size_t)(rowbase + m * 16 + l15) * DIM + lhi * 8;
#pragma unroll
        for (int g = 0; g < 4; ++g)
            a[m][g] = *reinterpret_cast<const bf16x8*>(arow + g * 32);
    }

    float esum[MREP][4];
#pragma unroll
    for (int m = 0; m < MREP; ++m)
#pragma unroll
        for (int j = 0; j < 4; ++j) esum[m][j] = 0.0f;

    const unsigned short* bcol = Xb + (size_t)(colbase + l15) * DIM + lhi * 8;

    bf16x8 bc[4];
#pragma unroll
    for (int g = 0; g < 4; ++g)
        bc[g] = *reinterpret_cast<const bf16x8*>(bcol + g * 32);

    for (int ct = 0; ct < NTILES; ++ct) {
        bf16x8 bn[4];
        const bool hasNext = (ct + 1 < NTILES);
        if (hasNext) {
            const unsigned short* p2 = bcol + (size_t)(ct + 1) * 16 * DIM;
#pragma unroll
            for (int g = 0; g < 4; ++g)
                bn[g] = *reinterpret_cast<const bf16x8*>(p2 + g * 32);
        }
#pragma unroll
        for (int m = 0; m < MREP; ++m) {
            f32x4 d = {0.0f, 0.0f, 0.0f, 0.0f};
#pragma unroll
            for (int g = 0; g < 4; ++g)
                d = __builtin_amdgcn_mfma_f32_16x16x32_bf16(a[m][g], bc[g], d, 0, 0, 0);
#pragma unroll
            for (int j = 0; j < 4; ++j)
                esum[m][j] += exp2_fast(d[j]);
        }
        if (hasNext) {
#pragma unroll
            for (int g = 0; g < 4; ++g) bc[g] = bn[g];
        }
    }

    // Reduce the 16 column-lanes (same lhi, varying l15); one slot per row.
#pragma unroll
    for (int m = 0; m < MREP; ++m) {
#pragma unroll
        for (int j = 0; j < 4; ++j) {
            float v = esum[m][j];
            v += __shfl_xor(v, 1, 64);
            v += __shfl_xor(v, 2, 64);
            v += __shfl_xor(v, 4, 64);
            v += __shfl_xor(v, 8, 64);
            if (l15 == 0) {
                int row = rowbase + m * 16 + lhi * 4 + j;
                partial[(size_t)cs * NROWS + row] = v * E1_F;
            }
        }
    }
}

// Kernel 3: exact f32 2x2 diagonal blocks + D_pos per pair.
__global__ __launch_bounds__(256) void k_pair(const float* __restrict__ X,
                                              float* __restrict__ blocksum,
                                              float* __restrict__ dpos) {
    int p = blockIdx.x * 256 + threadIdx.x;
    if (p >= NPAIR) return;
    const float4* a = reinterpret_cast<const float4*>(X + (size_t)(2 * p) * DIM);
    const float4* b = reinterpret_cast<const float4*>(X + (size_t)(2 * p + 1) * DIM);
    float d00 = 0.f, d01 = 0.f, d11 = 0.f;
#pragma unroll 8
    for (int i = 0; i < DIM / 4; ++i) {
        float4 av = a[i], bv = b[i];
        d00 += av.x * av.x + av.y * av.y + av.z * av.z + av.w * av.w;
        d01 += av.x * bv.x + av.y * bv.y + av.z * bv.z + av.w * bv.w;
        d11 += bv.x * bv.x + bv.y * bv.y + bv.z * bv.z + bv.w * bv.w;
    }
    float D01 = d01 * (1.0f / DIM);
    float e00 = __expf(d00 * (1.0f / DIM) + 1.0f);
    float e01 = __expf(D01 + 1.0f);
    float e11 = __expf(d11 * (1.0f / DIM) + 1.0f);
    blocksum[p] = e00 + 2.0f * e01 + e11;
    dpos[p] = D01;
}

// Kernel 4a: per-pair J^2, block-reduced into lpart[16].
__global__ __launch_bounds__(256) void k_loss1(const float* __restrict__ partial,
                                               const float* __restrict__ blocksum,
                                               const float* __restrict__ dpos,
                                               float* __restrict__ lpart) {
    int p = blockIdx.x * 256 + threadIdx.x;   // 0..4095
    float S = 0.0f;
    const float* pp = partial + 2 * p;
#pragma unroll 8
    for (int cs = 0; cs < CSPLIT; ++cs)
        S += pp[cs * NROWS] + pp[cs * NROWS + 1];
    S -= blocksum[p];
    float J = logf(1e-8f + S) - dpos[p];
    float t = fmaxf(J, 0.0f);
    float acc = t * t;

    __shared__ float red[4];
    float v = acc;
#pragma unroll
    for (int off = 32; off >= 1; off >>= 1) v += __shfl_down(v, off, 64);
    if ((threadIdx.x & 63) == 0) red[threadIdx.x >> 6] = v;
    __syncthreads();
    if (threadIdx.x == 0)
        lpart[blockIdx.x] = red[0] + red[1] + red[2] + red[3];
}

// Kernel 4b: final 16-element sum -> loss.
__global__ __launch_bounds__(64) void k_final(const float* __restrict__ lpart,
                                              float* __restrict__ out) {
    float v = (threadIdx.x < 16) ? lpart[threadIdx.x] : 0.0f;
#pragma unroll
    for (int off = 8; off >= 1; off >>= 1) v += __shfl_down(v, off, 64);
    if (threadIdx.x == 0) out[0] = v * (1.0f / (2.0f * NPAIR));
}

extern "C" void kernel_launch(void* const* d_in, const int* in_sizes, int n_in,
                              void* d_out, int out_size, void* d_ws, size_t ws_size,
                              hipStream_t stream) {
    const float* X = (const float*)d_in[0];
    float* out = (float*)d_out;

    unsigned short* Xa = (unsigned short*)d_ws;                        // 2 MB
    unsigned short* Xb = Xa + (size_t)NROWS * DIM;                     // 2 MB
    float* partial = (float*)(Xb + (size_t)NROWS * DIM);               // 2 MB
    float* blocksum = partial + (size_t)CSPLIT * NROWS;                // 16 KB
    float* dpos = blocksum + NPAIR;                                    // 16 KB
    float* lpart = dpos + NPAIR;                                       // 64 B

    k_convert<<<dim3((NROWS * DIM / 4) / 256), dim3(256), 0, stream>>>(X, Xa, Xb);
    k_rowsum<<<dim3(NROWS / ROWS_PER_BLOCK, CSPLIT), dim3(256), 0, stream>>>(Xa, Xb, partial);
    k_pair<<<dim3(NPAIR / 256), dim3(256), 0, stream>>>(X, blocksum, dpos);
    k_loss1<<<dim3(NPAIR / 256), dim3(256), 0, stream>>>(partial, blocksum, dpos, lpart);
    k_final<<<dim3(1), dim3(64), 0, stream>>>(lpart, out);
}

// Round 3
// 62.249 us; speedup vs baseline: 2.3574x; 2.3574x over previous
//
#include <hip/hip_runtime.h>
#include <hip/hip_bf16.h>

#define NROWS 8192
#define DIM   128
#define NPAIR (NROWS / 2)
#define CSPLIT 32
#define COLS_PER_CS (NROWS / CSPLIT)    // 256
#define NTILES (COLS_PER_CS / 16)       // 16
#define MREP   4                        // 16-row blocks per wave -> 64 rows/wave
#define ROWS_PER_BLOCK 256              // 4 waves * 64 rows

typedef __attribute__((ext_vector_type(8))) short bf16x8;
typedef __attribute__((ext_vector_type(4))) float f32x4;

__device__ inline float exp2_fast(float x) {
#if __has_builtin(__builtin_amdgcn_exp2f)
    return __builtin_amdgcn_exp2f(x);
#else
    return exp2f(x);
#endif
}

__device__ inline unsigned short f2bf(float f) {
    unsigned int u = __float_as_uint(f);
    unsigned int r = (u + 0x7fffu + ((u >> 16) & 1u)) >> 16;
    return (unsigned short)r;
}

// exp(dot/128 + 1) = e * exp2(dot * SCL), SCL = log2(e)/128.
// SCL baked into the A operand (Xa): inner loop is exp2 + add only.
#define SCL_F 0.0112710550069450f      // 1.4426950408889634 / 128
#define E1_F  2.7182818284590452f

// Kernel 1: X (f32) -> Xa (bf16, scaled by SCL) and Xb (bf16, unscaled).
__global__ __launch_bounds__(256) void k_convert(const float* __restrict__ X,
                                                 unsigned short* __restrict__ Xa,
                                                 unsigned short* __restrict__ Xb) {
    int id = blockIdx.x * 256 + threadIdx.x;       // 0 .. 262143
    float4 v = reinterpret_cast<const float4*>(X)[id];
    ushort4 oa, ob;
    oa.x = f2bf(v.x * SCL_F); oa.y = f2bf(v.y * SCL_F);
    oa.z = f2bf(v.z * SCL_F); oa.w = f2bf(v.w * SCL_F);
    ob.x = f2bf(v.x); ob.y = f2bf(v.y); ob.z = f2bf(v.z); ob.w = f2bf(v.w);
    reinterpret_cast<ushort4*>(Xa)[id] = oa;
    reinterpret_cast<ushort4*>(Xb)[id] = ob;
}

// Kernel 2: partial[cs][r] = e * sum over 256-col chunk cs of exp2(SCL*dot).
__global__ __launch_bounds__(256) void k_rowsum(const unsigned short* __restrict__ Xa,
                                                const unsigned short* __restrict__ Xb,
                                                float* __restrict__ partial) {
    const int wave = threadIdx.x >> 6;
    const int lane = threadIdx.x & 63;
    const int l15  = lane & 15;
    const int lhi  = lane >> 4;   // 0..3
    const int rowbase = blockIdx.x * ROWS_PER_BLOCK + wave * (MREP * 16);
    const int cs = blockIdx.y;
    const int colbase = cs * COLS_PER_CS;

    // A fragments (scaled copy): MREP row-blocks x 4 k-blocks, 16B each.
    bf16x8 a[MREP][4];
#pragma unroll
    for (int m = 0; m < MREP; ++m) {
        const unsigned short* arow = Xa + (size_t)(rowbase + m * 16 + l15) * DIM + lhi * 8;
#pragma unroll
        for (int g = 0; g < 4; ++g)
            a[m][g] = *reinterpret_cast<const bf16x8*>(arow + g * 32);
    }

    float esum[MREP][4];
#pragma unroll
    for (int m = 0; m < MREP; ++m)
#pragma unroll
        for (int j = 0; j < 4; ++j) esum[m][j] = 0.0f;

    const unsigned short* bcol = Xb + (size_t)(colbase + l15) * DIM + lhi * 8;

    for (int ct = 0; ct < NTILES; ++ct) {
        const unsigned short* bp = bcol + (size_t)ct * 16 * DIM;
        bf16x8 b[4];
#pragma unroll
        for (int g = 0; g < 4; ++g)
            b[g] = *reinterpret_cast<const bf16x8*>(bp + g * 32);
#pragma unroll
        for (int m = 0; m < MREP; ++m) {
            f32x4 d = {0.0f, 0.0f, 0.0f, 0.0f};
#pragma unroll
            for (int g = 0; g < 4; ++g)
                d = __builtin_amdgcn_mfma_f32_16x16x32_bf16(a[m][g], b[g], d, 0, 0, 0);
#pragma unroll
            for (int j = 0; j < 4; ++j)
                esum[m][j] += exp2_fast(d[j]);
        }
    }

    // Reduce the 16 column-lanes (same lhi, varying l15); one slot per row.
#pragma unroll
    for (int m = 0; m < MREP; ++m) {
#pragma unroll
        for (int j = 0; j < 4; ++j) {
            float v = esum[m][j];
            v += __shfl_xor(v, 1, 64);
            v += __shfl_xor(v, 2, 64);
            v += __shfl_xor(v, 4, 64);
            v += __shfl_xor(v, 8, 64);
            if (l15 == 0) {
                int row = rowbase + m * 16 + lhi * 4 + j;
                partial[(size_t)cs * NROWS + row] = v * E1_F;
            }
        }
    }
}

// Kernel 3: exact f32 2x2 diagonal blocks + D_pos per pair.
__global__ __launch_bounds__(256) void k_pair(const float* __restrict__ X,
                                              float* __restrict__ blocksum,
                                              float* __restrict__ dpos) {
    int p = blockIdx.x * 256 + threadIdx.x;
    if (p >= NPAIR) return;
    const float4* a = reinterpret_cast<const float4*>(X + (size_t)(2 * p) * DIM);
    const float4* b = reinterpret_cast<const float4*>(X + (size_t)(2 * p + 1) * DIM);
    float d00 = 0.f, d01 = 0.f, d11 = 0.f;
#pragma unroll 8
    for (int i = 0; i < DIM / 4; ++i) {
        float4 av = a[i], bv = b[i];
        d00 += av.x * av.x + av.y * av.y + av.z * av.z + av.w * av.w;
        d01 += av.x * bv.x + av.y * bv.y + av.z * bv.z + av.w * bv.w;
        d11 += bv.x * bv.x + bv.y * bv.y + bv.z * bv.z + bv.w * bv.w;
    }
    float D01 = d01 * (1.0f / DIM);
    float e00 = __expf(d00 * (1.0f / DIM) + 1.0f);
    float e01 = __expf(D01 + 1.0f);
    float e11 = __expf(d11 * (1.0f / DIM) + 1.0f);
    blocksum[p] = e00 + 2.0f * e01 + e11;
    dpos[p] = D01;
}

// Kernel 4a: per-pair J^2, block-reduced into lpart[16].
__global__ __launch_bounds__(256) void k_loss1(const float* __restrict__ partial,
                                               const float* __restrict__ blocksum,
                                               const float* __restrict__ dpos,
                                               float* __restrict__ lpart) {
    int p = blockIdx.x * 256 + threadIdx.x;   // 0..4095
    float S = 0.0f;
    const float* pp = partial + 2 * p;
#pragma unroll 8
    for (int cs = 0; cs < CSPLIT; ++cs)
        S += pp[cs * NROWS] + pp[cs * NROWS + 1];
    S -= blocksum[p];
    float J = logf(1e-8f + S) - dpos[p];
    float t = fmaxf(J, 0.0f);
    float acc = t * t;

    __shared__ float red[4];
    float v = acc;
#pragma unroll
    for (int off = 32; off >= 1; off >>= 1) v += __shfl_down(v, off, 64);
    if ((threadIdx.x & 63) == 0) red[threadIdx.x >> 6] = v;
    __syncthreads();
    if (threadIdx.x == 0)
        lpart[blockIdx.x] = red[0] + red[1] + red[2] + red[3];
}

// Kernel 4b: final 16-element sum -> loss.
__global__ __launch_bounds__(64) void k_final(const float* __restrict__ lpart,
                                              float* __restrict__ out) {
    float v = (threadIdx.x < 16) ? lpart[threadIdx.x] : 0.0f;
#pragma unroll
    for (int off = 8; off >= 1; off >>= 1) v += __shfl_down(v, off, 64);
    if (threadIdx.x == 0) out[0] = v * (1.0f / (2.0f * NPAIR));
}

extern "C" void kernel_launch(void* const* d_in, const int* in_sizes, int n_in,
                              void* d_out, int out_size, void* d_ws, size_t ws_size,
                              hipStream_t stream) {
    const float* X = (const float*)d_in[0];
    float* out = (float*)d_out;

    unsigned short* Xa = (unsigned short*)d_ws;                        // 2 MB
    unsigned short* Xb = Xa + (size_t)NROWS * DIM;                     // 2 MB
    float* partial = (float*)(Xb + (size_t)NROWS * DIM);               // 1 MB
    float* blocksum = partial + (size_t)CSPLIT * NROWS;                // 16 KB
    float* dpos = blocksum + NPAIR;                                    // 16 KB
    float* lpart = dpos + NPAIR;                                       // 64 B

    k_convert<<<dim3((NROWS * DIM / 4) / 256), dim3(256), 0, stream>>>(X, Xa, Xb);
    k_rowsum<<<dim3(NROWS / ROWS_PER_BLOCK, CSPLIT), dim3(256), 0, stream>>>(Xa, Xb, partial);
    k_pair<<<dim3(NPAIR / 256), dim3(256), 0, stream>>>(X, blocksum, dpos);
    k_loss1<<<dim3(NPAIR / 256), dim3(256), 0, stream>>>(partial, blocksum, dpos, lpart);
    k_final<<<dim3(1), dim3(64), 0, stream>>>(lpart, out);
}